// Round 6
// baseline (671.268 us; speedup 1.0000x reference)
//
#include <hip/hip_runtime.h>
#include <hip/hip_bf16.h>

// SwinBlock r6: revert MLP to BW-bound gemm128 chain (fused mlp2+LN2+res),
// fold window-gather+cvt into qkv A-staging, grid-swap for L2 A-reuse.
// B=32 H=W=56 C=256 NH=8 HD=32 WS=7 SS=3 L=49 nWin=64 -> 2048 windows, M=100352 rows.

typedef unsigned short ushort_t;
typedef short bf16x8 __attribute__((ext_vector_type(8)));
typedef float f32x4 __attribute__((ext_vector_type(4)));

__device__ __forceinline__ float bf2f(unsigned short u) {
    union { unsigned int i; float f; } x; x.i = ((unsigned int)u) << 16; return x.f;
}
__device__ __forceinline__ unsigned short f2bf(float f) {
    union { float f; unsigned int i; } x; x.f = f;
    unsigned int r = x.i + 0x7fffu + ((x.i >> 16) & 1u);   // RNE
    return (unsigned short)(r >> 16);
}
__device__ __forceinline__ bf16x8 pack8(float4 a, float4 b) {
    bf16x8 r;
    r[0] = (short)f2bf(a.x); r[1] = (short)f2bf(a.y);
    r[2] = (short)f2bf(a.z); r[3] = (short)f2bf(a.w);
    r[4] = (short)f2bf(b.x); r[5] = (short)f2bf(b.y);
    r[6] = (short)f2bf(b.z); r[7] = (short)f2bf(b.w);
    return r;
}
__device__ __forceinline__ void gl_lds16(const ushort_t* g, ushort_t* l) {
    __builtin_amdgcn_global_load_lds((const __attribute__((address_space(1))) void*)g,
                                     (__attribute__((address_space(3))) void*)l, 16, 0, 0);
}
// exact-erf GELU via Abramowitz-Stegun 7.1.26 (max |err| 1.5e-7)
__device__ __forceinline__ float gelu_f(float v) {
    float s = v * 0.70710678118654752f;
    float ax = fabsf(s);
    float t = __builtin_amdgcn_rcpf(1.0f + 0.3275911f * ax);
    float poly = ((((1.061405429f * t - 1.453152027f) * t + 1.421413741f) * t
                   - 0.284496736f) * t + 0.254829592f) * t;
    float y = 1.0f - poly * __expf(-ax * ax);
    float e = (s < 0.f) ? -y : y;
    return 0.5f * v * (1.0f + e);
}

// row m of the windowed/shifted activation -> element offset into x[B,H,W,C]
__device__ __forceinline__ long swin_src_off(int m) {
    int n = m / 49, l = m - n * 49;
    int b = n >> 6, win = n & 63;
    int wh = win >> 3, ww = win & 7;
    int i = l / 7, j = l - i * 7;
    int hs = wh * 7 + i + 3; if (hs >= 56) hs -= 56;   // roll(-3)
    int ws = ww * 7 + j + 3; if (ws >= 56) ws -= 56;
    return ((long)(b * 56 + hs) * 56 + ws) * 256;
}

// ---------------- prep: weights fp32 -> bf16 [N][K] (optional transpose) ----
template<int SRCT>
__global__ __launch_bounds__(256)
void convW(const float* __restrict__ src, ushort_t* __restrict__ dst, int N, int kshift)
{
    int idx = blockIdx.x * 256 + threadIdx.x;
    int kk = idx & ((1 << kshift) - 1), nn = idx >> kshift;
    float v = SRCT ? src[(long)kk * N + nn] : src[idx];
    dst[idx] = f2bf(v);
}

// ---------------- GEMM 128x128, BK=32, global_load_lds staging ----------------
// blockIdx.x = col tile (fast) -> consecutive blocks reuse the A row-stripe in L2.
// AMODE 0: A bf16 [M][K] via gl_lds.  AMODE 1: A fp32, rows gathered via
// swin_src_off, reg-staged + packed to bf16 (K==256).
template<int ACT, int AMODE>
__global__ __launch_bounds__(256)
void gemm128(const void* __restrict__ Av, const ushort_t* __restrict__ W,
             const float* __restrict__ bias, ushort_t* __restrict__ C,
             int M, int N, int K)
{
    __shared__ ushort_t As[128 * 32];
    __shared__ ushort_t Bs[128 * 32];
    const int t = threadIdx.x, lane = t & 63, wave = t >> 6;
    const int row0 = blockIdx.y * 128, col0 = blockIdx.x * 128;
    const int wm = (wave >> 1) * 64, wn = (wave & 1) * 64;

    const ushort_t* ag0; const ushort_t* ag1;
    const float* af0; const float* af1;
    if (AMODE == 0) {
        ag0 = (const ushort_t*)Av + (long)(row0 + (t >> 2)) * K + (t & 3) * 8;
        ag1 = (const ushort_t*)Av + (long)(row0 + 64 + (t >> 2)) * K + (t & 3) * 8;
    } else {
        af0 = (const float*)Av + swin_src_off(row0 + (t >> 2)) + (t & 3) * 8;
        af1 = (const float*)Av + swin_src_off(row0 + 64 + (t >> 2)) + (t & 3) * 8;
    }
    const ushort_t* bg0 = W + (long)(col0 + (t >> 2)) * K + (t & 3) * 8;
    const ushort_t* bg1 = W + (long)(col0 + 64 + (t >> 2)) * K + (t & 3) * 8;
    ushort_t* la0 = &As[t * 8];        ushort_t* la1 = &As[2048 + t * 8];
    ushort_t* lb0 = &Bs[t * 8];        ushort_t* lb1 = &Bs[2048 + t * 8];

    f32x4 acc[4][4] = {};
    for (int k0 = 0; k0 < K; k0 += 32) {
        bf16x8 a0, a1;
        if (AMODE == 1) {   // issue loads before the barrier: latency overlaps
            const float* p0 = af0 + k0;
            const float* p1 = af1 + k0;
            float4 x0 = *(const float4*)p0, x1 = *(const float4*)(p0 + 4);
            float4 x2 = *(const float4*)p1, x3 = *(const float4*)(p1 + 4);
            a0 = pack8(x0, x1); a1 = pack8(x2, x3);
        }
        __syncthreads();                 // previous tile fully consumed
        if (AMODE == 0) {
            gl_lds16(ag0 + k0, la0);
            gl_lds16(ag1 + k0, la1);
        } else {
            *(bf16x8*)la0 = a0;
            *(bf16x8*)la1 = a1;
        }
        gl_lds16(bg0 + k0, lb0);
        gl_lds16(bg1 + k0, lb1);
        __syncthreads();                 // staging resident
        bf16x8 af[4], bw[4];
        #pragma unroll
        for (int i = 0; i < 4; i++) {
            af[i] = *(const bf16x8*)&As[(wm + i * 16 + (lane & 15)) * 32 + (lane >> 4) * 8];
            bw[i] = *(const bf16x8*)&Bs[(wn + i * 16 + (lane & 15)) * 32 + (lane >> 4) * 8];
        }
        #pragma unroll
        for (int mi = 0; mi < 4; mi++)
            #pragma unroll
            for (int ni = 0; ni < 4; ni++)
                acc[mi][ni] = __builtin_amdgcn_mfma_f32_16x16x32_bf16(af[mi], bw[ni], acc[mi][ni], 0, 0, 0);
    }
    #pragma unroll
    for (int mi = 0; mi < 4; mi++)
        #pragma unroll
        for (int ni = 0; ni < 4; ni++) {
            const int c = col0 + wn + ni * 16 + (lane & 15);
            const float bv = bias[c];
            #pragma unroll
            for (int r = 0; r < 4; r++) {
                const int rr = row0 + wm + mi * 16 + (lane >> 4) * 4 + r;
                float v = acc[mi][ni][r] + bv;
                if (ACT) v = gelu_f(v);
                C[(long)rr * N + c] = f2bf(v);
            }
        }
}

// ---------------- MFMA attention: one wave per (window, head) ----------------
__global__ __launch_bounds__(64)
void attn_mfma(const ushort_t* __restrict__ qkv, const float* __restrict__ rpb,
               ushort_t* __restrict__ out)
{
    __shared__ ushort_t v_t[32 * 72];    // V^T [d][j], pad 72
    __shared__ ushort_t p_lds[64 * 72];  // P   [i][j], pad 72
    __shared__ float bias_s[169];

    const int blk = blockIdx.x;
    const int n = blk >> 3, h = blk & 7;
    const int l = threadIdx.x;           // 0..63
    const long wbase = (long)n * 49 * 768 + h * 32;
    const float scale = 0.17677669529663687f;   // 32^-0.5

    {
        int j = min(l, 48);
        const ushort_t* vr = qkv + wbase + (long)j * 768 + 512;
        #pragma unroll
        for (int c = 0; c < 4; c++) {
            bf16x8 vv = *(const bf16x8*)(vr + c * 8);
            #pragma unroll
            for (int e = 0; e < 8; e++) v_t[(c * 8 + e) * 72 + l] = (ushort_t)vv[e];
        }
    }
    for (int idx = l; idx < 169; idx += 64) bias_s[idx] = rpb[idx * 8 + h];
    __syncthreads();

    f32x4 s[4][4] = {};
    {
        bf16x8 aq[4], bk[4];
        #pragma unroll
        for (int mt = 0; mt < 4; mt++) {
            int i = min(mt * 16 + (l & 15), 48);
            aq[mt] = *(const bf16x8*)(qkv + wbase + (long)i * 768 + (l >> 4) * 8);
        }
        #pragma unroll
        for (int nt = 0; nt < 4; nt++) {
            int j = min(nt * 16 + (l & 15), 48);
            bk[nt] = *(const bf16x8*)(qkv + wbase + (long)j * 768 + 256 + (l >> 4) * 8);
        }
        #pragma unroll
        for (int mt = 0; mt < 4; mt++)
            #pragma unroll
            for (int nt = 0; nt < 4; nt++)
                s[mt][nt] = __builtin_amdgcn_mfma_f32_16x16x32_bf16(aq[mt], bk[nt], s[mt][nt], 0, 0, 0);
    }

    const int win = n & 63, wh = win >> 3, ww = win & 7;
    int yj[4], xj[4], regj[4]; bool jv[4];
    #pragma unroll
    for (int nt = 0; nt < 4; nt++) {
        int j = nt * 16 + (l & 15);
        jv[nt] = (j <= 48);
        int jc = min(j, 48);
        yj[nt] = jc / 7; xj[nt] = jc - yj[nt] * 7;
        int hs = wh * 7 + yj[nt], wsx = ww * 7 + xj[nt];
        regj[nt] = (hs < 49 ? 0 : (hs < 53 ? 1 : 2)) * 3 + (wsx < 49 ? 0 : (wsx < 53 ? 1 : 2));
    }
    float rinv[4][4];
    #pragma unroll
    for (int mt = 0; mt < 4; mt++) {
        #pragma unroll
        for (int r = 0; r < 4; r++) {
            int i = mt * 16 + (l >> 4) * 4 + r;
            int ic = min(i, 48);
            int yi = ic / 7, xi = ic - yi * 7;
            int hs = wh * 7 + yi, wsx = ww * 7 + xi;
            int regi = (hs < 49 ? 0 : (hs < 53 ? 1 : 2)) * 3 + (wsx < 49 ? 0 : (wsx < 53 ? 1 : 2));
            float val[4];
            #pragma unroll
            for (int nt = 0; nt < 4; nt++) {
                float v = s[mt][nt][r] * scale + bias_s[(yi - yj[nt] + 6) * 13 + (xi - xj[nt] + 6)];
                if (regi != regj[nt]) v -= 100.f;
                val[nt] = jv[nt] ? v : -1e30f;
            }
            float mx = fmaxf(fmaxf(val[0], val[1]), fmaxf(val[2], val[3]));
            #pragma unroll
            for (int off = 1; off <= 8; off <<= 1) mx = fmaxf(mx, __shfl_xor(mx, off));
            float sum = 0.f;
            #pragma unroll
            for (int nt = 0; nt < 4; nt++) { val[nt] = __expf(val[nt] - mx); sum += val[nt]; }
            #pragma unroll
            for (int off = 1; off <= 8; off <<= 1) sum += __shfl_xor(sum, off);
            rinv[mt][r] = 1.0f / sum;
            #pragma unroll
            for (int nt = 0; nt < 4; nt++)
                p_lds[i * 72 + nt * 16 + (l & 15)] = f2bf(val[nt]);
        }
    }
    __syncthreads();

    f32x4 o[4][2] = {};
    #pragma unroll
    for (int ks = 0; ks < 2; ks++) {
        bf16x8 pa[4], vb[2];
        #pragma unroll
        for (int mt = 0; mt < 4; mt++)
            pa[mt] = *(const bf16x8*)&p_lds[(mt * 16 + (l & 15)) * 72 + ks * 32 + (l >> 4) * 8];
        #pragma unroll
        for (int nt = 0; nt < 2; nt++)
            vb[nt] = *(const bf16x8*)&v_t[(nt * 16 + (l & 15)) * 72 + ks * 32 + (l >> 4) * 8];
        #pragma unroll
        for (int mt = 0; mt < 4; mt++)
            #pragma unroll
            for (int nt = 0; nt < 2; nt++)
                o[mt][nt] = __builtin_amdgcn_mfma_f32_16x16x32_bf16(pa[mt], vb[nt], o[mt][nt], 0, 0, 0);
    }
    #pragma unroll
    for (int mt = 0; mt < 4; mt++)
        #pragma unroll
        for (int r = 0; r < 4; r++) {
            int i = mt * 16 + (l >> 4) * 4 + r;
            if (i < 49) {
                float rs = rinv[mt][r];
                #pragma unroll
                for (int nt = 0; nt < 2; nt++) {
                    int d = nt * 16 + (l & 15);
                    out[((long)n * 49 + i) * 256 + h * 32 + d] = f2bf(o[mt][nt][r] * rs);
                }
            }
        }
}

// ------------- fused proj GEMM (128x256, full rows) + LN1 + residual -------------
__global__ __launch_bounds__(512)
void projln1(const ushort_t* __restrict__ A, const ushort_t* __restrict__ W,
             const float* __restrict__ pb, const float* __restrict__ x,
             const float* __restrict__ gamma, const float* __restrict__ beta,
             float* __restrict__ x1f, ushort_t* __restrict__ x1b)
{
    __shared__ ushort_t As[128 * 32];
    __shared__ ushort_t Bs[256 * 32];
    __shared__ float red_s[128][4];
    __shared__ float red_ss[128][4];
    __shared__ int srow_s[128];
    const int t = threadIdx.x, lane = t & 63, w = t >> 6;
    const int row0 = blockIdx.x * 128;
    const int wm = (w >> 2) * 64, wn = (w & 3) * 64;

    if (t < 128) srow_s[t] = (int)(swin_src_off(row0 + t) >> 8);

    const ushort_t* ag = A + (long)(row0 + (t >> 2)) * 256 + (t & 3) * 8;
    f32x4 acc[4][4] = {};
    for (int k0 = 0; k0 < 256; k0 += 32) {
        __syncthreads();
        gl_lds16(ag + k0, &As[t * 8]);
        #pragma unroll
        for (int i = 0; i < 2; i++) {
            int u = i * 512 + t;
            gl_lds16(W + (long)(u >> 2) * 256 + k0 + (u & 3) * 8, &Bs[u * 8]);
        }
        __syncthreads();
        bf16x8 af[4], bw[4];
        #pragma unroll
        for (int i2 = 0; i2 < 4; i2++) {
            af[i2] = *(const bf16x8*)&As[(wm + i2 * 16 + (lane & 15)) * 32 + (lane >> 4) * 8];
            bw[i2] = *(const bf16x8*)&Bs[(wn + i2 * 16 + (lane & 15)) * 32 + (lane >> 4) * 8];
        }
        #pragma unroll
        for (int mi = 0; mi < 4; mi++)
            #pragma unroll
            for (int ni = 0; ni < 4; ni++)
                acc[mi][ni] = __builtin_amdgcn_mfma_f32_16x16x32_bf16(af[mi], bw[ni], acc[mi][ni], 0, 0, 0);
    }
    float pbv[4], g1v[4], be1v[4];
    #pragma unroll
    for (int ni = 0; ni < 4; ni++) {
        int col = wn + ni * 16 + (lane & 15);
        pbv[ni] = pb[col]; g1v[ni] = gamma[col]; be1v[ni] = beta[col];
    }
    #pragma unroll
    for (int mi = 0; mi < 4; mi++)
        #pragma unroll
        for (int rr = 0; rr < 4; rr++) {
            float s = 0.f, ss = 0.f;
            #pragma unroll
            for (int ni = 0; ni < 4; ni++) {
                float v = acc[mi][ni][rr] + pbv[ni];
                acc[mi][ni][rr] = v; s += v; ss += v * v;
            }
            #pragma unroll
            for (int off = 1; off <= 8; off <<= 1) { s += __shfl_xor(s, off); ss += __shfl_xor(ss, off); }
            if ((lane & 15) == 0) {
                int r = wm + mi * 16 + (lane >> 4) * 4 + rr;
                red_s[r][w & 3] = s; red_ss[r][w & 3] = ss;
            }
        }
    __syncthreads();
    #pragma unroll
    for (int mi = 0; mi < 4; mi++)
        #pragma unroll
        for (int rr = 0; rr < 4; rr++) {
            const int r = wm + mi * 16 + (lane >> 4) * 4 + rr;
            const float s = red_s[r][0] + red_s[r][1] + red_s[r][2] + red_s[r][3];
            const float ss = red_ss[r][0] + red_ss[r][1] + red_ss[r][2] + red_ss[r][3];
            const float mu = s * (1.0f / 256.0f);
            const float rstd = rsqrtf(ss * (1.0f / 256.0f) - mu * mu + 1e-5f);
            const long sp = srow_s[r];
            #pragma unroll
            for (int ni = 0; ni < 4; ni++) {
                int col = wn + ni * 16 + (lane & 15);
                float o = x[sp * 256 + col] + (acc[mi][ni][rr] - mu) * rstd * g1v[ni] + be1v[ni];
                x1f[sp * 256 + col] = o;
                x1b[sp * 256 + col] = f2bf(o);
            }
        }
}

// ------------- fused mlp2 GEMM (128x256, K=1024) + LN2 + residual, fp32 out ----
__global__ __launch_bounds__(512)
void mlp2ln2(const ushort_t* __restrict__ A, const ushort_t* __restrict__ W,
             const float* __restrict__ pb, const float* __restrict__ x1f,
             const float* __restrict__ gamma, const float* __restrict__ beta,
             float* __restrict__ out)
{
    __shared__ ushort_t As[128 * 32];
    __shared__ ushort_t Bs[256 * 32];
    __shared__ float red_s[128][4];
    __shared__ float red_ss[128][4];
    const int t = threadIdx.x, lane = t & 63, w = t >> 6;
    const int row0 = blockIdx.x * 128;
    const int wm = (w >> 2) * 64, wn = (w & 3) * 64;

    const ushort_t* ag = A + (long)(row0 + (t >> 2)) * 1024 + (t & 3) * 8;
    f32x4 acc[4][4] = {};
    for (int k0 = 0; k0 < 1024; k0 += 32) {
        __syncthreads();
        gl_lds16(ag + k0, &As[t * 8]);
        #pragma unroll
        for (int i = 0; i < 2; i++) {
            int u = i * 512 + t;
            gl_lds16(W + (long)(u >> 2) * 1024 + k0 + (u & 3) * 8, &Bs[u * 8]);
        }
        __syncthreads();
        bf16x8 af[4], bw[4];
        #pragma unroll
        for (int i2 = 0; i2 < 4; i2++) {
            af[i2] = *(const bf16x8*)&As[(wm + i2 * 16 + (lane & 15)) * 32 + (lane >> 4) * 8];
            bw[i2] = *(const bf16x8*)&Bs[(wn + i2 * 16 + (lane & 15)) * 32 + (lane >> 4) * 8];
        }
        #pragma unroll
        for (int mi = 0; mi < 4; mi++)
            #pragma unroll
            for (int ni = 0; ni < 4; ni++)
                acc[mi][ni] = __builtin_amdgcn_mfma_f32_16x16x32_bf16(af[mi], bw[ni], acc[mi][ni], 0, 0, 0);
    }
    float pbv[4], g2v[4], be2v[4];
    #pragma unroll
    for (int ni = 0; ni < 4; ni++) {
        int col = wn + ni * 16 + (lane & 15);
        pbv[ni] = pb[col]; g2v[ni] = gamma[col]; be2v[ni] = beta[col];
    }
    #pragma unroll
    for (int mi = 0; mi < 4; mi++)
        #pragma unroll
        for (int rr = 0; rr < 4; rr++) {
            float s = 0.f, ss = 0.f;
            #pragma unroll
            for (int ni = 0; ni < 4; ni++) {
                float v = acc[mi][ni][rr] + pbv[ni];
                acc[mi][ni][rr] = v; s += v; ss += v * v;
            }
            #pragma unroll
            for (int off = 1; off <= 8; off <<= 1) { s += __shfl_xor(s, off); ss += __shfl_xor(ss, off); }
            if ((lane & 15) == 0) {
                int r = wm + mi * 16 + (lane >> 4) * 4 + rr;
                red_s[r][w & 3] = s; red_ss[r][w & 3] = ss;
            }
        }
    __syncthreads();
    #pragma unroll
    for (int mi = 0; mi < 4; mi++)
        #pragma unroll
        for (int rr = 0; rr < 4; rr++) {
            const int r = wm + mi * 16 + (lane >> 4) * 4 + rr;
            const float s = red_s[r][0] + red_s[r][1] + red_s[r][2] + red_s[r][3];
            const float ss = red_ss[r][0] + red_ss[r][1] + red_ss[r][2] + red_ss[r][3];
            const float mu = s * (1.0f / 256.0f);
            const float rstd = rsqrtf(ss * (1.0f / 256.0f) - mu * mu + 1e-5f);
            const long gr = row0 + r;
            #pragma unroll
            for (int ni = 0; ni < 4; ni++) {
                int col = wn + ni * 16 + (lane & 15);
                out[gr * 256 + col] = x1f[gr * 256 + col]
                                    + (acc[mi][ni][rr] - mu) * rstd * g2v[ni] + be2v[ni];
            }
        }
}

extern "C" void kernel_launch(void* const* d_in, const int* in_sizes, int n_in,
                              void* d_out, int out_size, void* d_ws, size_t ws_size,
                              hipStream_t stream) {
    const float* x      = (const float*)d_in[0];
    const float* qkv_w  = (const float*)d_in[1];
    const float* qkv_b  = (const float*)d_in[2];
    const float* proj_w = (const float*)d_in[3];
    const float* proj_b = (const float*)d_in[4];
    const float* rpb    = (const float*)d_in[5];
    const float* gamma1 = (const float*)d_in[6];
    const float* beta1  = (const float*)d_in[7];
    const float* w1     = (const float*)d_in[8];
    const float* b1     = (const float*)d_in[9];
    const float* w2     = (const float*)d_in[10];
    const float* b2     = (const float*)d_in[11];
    const float* gamma2 = (const float*)d_in[12];
    const float* beta2  = (const float*)d_in[13];
    float* outf = (float*)d_out;

    // d_out as bf16 scratch until the final fp32 write:
    char* ob = (char*)d_out;
    ushort_t* attnout = (ushort_t*)ob;                    // [0,51.4M) attn -> projln1 (dead before mlp2ln2 writes)

    char* ws = (char*)d_ws;
    ushort_t* qkvb  = (ushort_t*)ws;                      // [0,154.1M)  qkv -> attn
    float*    x1f   = (float*)ws;                         // [0,102.8M)  projln1 -> mlp2ln2 (qkvb dead)
    ushort_t* x1b   = (ushort_t*)(ws + 102760448ULL);     // [102.8,154.1M)
    ushort_t* hbuf  = (ushort_t*)(ws + 154140672ULL);     // [154.1,205.5M) per-chunk hidden
    ushort_t* wqkvb = (ushort_t*)(ws + 205520896ULL);     // bf16 weights [N][K]
    ushort_t* wprojb= (ushort_t*)(ws + 205914112ULL);
    ushort_t* w1t   = (ushort_t*)(ws + 206045184ULL);
    ushort_t* w2t   = (ushort_t*)(ws + 206569472ULL);

    const int M = 100352, MC = 25088;
    dim3 blk(256);
    // prep: bf16 weights
    convW<0><<<dim3(768),  blk, 0, stream>>>(qkv_w,  wqkvb,  768,  8);   // [768][256]
    convW<0><<<dim3(256),  blk, 0, stream>>>(proj_w, wprojb, 256,  8);   // [256][256]
    convW<1><<<dim3(1024), blk, 0, stream>>>(w1,     w1t,    1024, 8);   // -> [1024][256]
    convW<1><<<dim3(1024), blk, 0, stream>>>(w2,     w2t,    256, 10);   // -> [256][1024]
    // 1. qkv = gather(x) @ Wqkv^T + b   (fp32 A gathered+packed in-kernel)
    gemm128<0, 1><<<dim3(6, 784), blk, 0, stream>>>(x, wqkvb, qkv_b, qkvb, M, 768, 256);
    // 2. windowed attention
    attn_mfma<<<dim3(16384), dim3(64), 0, stream>>>(qkvb, rpb, attnout);
    // 3. proj + LN1 + residual (writes x1f fp32 + x1b bf16, scattered to natural order)
    projln1<<<dim3(784), dim3(512), 0, stream>>>(attnout, wprojb, proj_b, x,
                                                 gamma1, beta1, x1f, x1b);
    // 4/5. MLP in 4 M-chunks (h-chunk stays L3-resident between the two GEMMs)
    for (int c4 = 0; c4 < 4; c4++) {
        const long off = (long)c4 * MC * 256;
        gemm128<1, 0><<<dim3(8, 196), blk, 0, stream>>>(x1b + off, w1t, b1, hbuf, MC, 1024, 256);
        mlp2ln2<<<dim3(196), dim3(512), 0, stream>>>(hbuf, w2t, b2, x1f + off,
                                                     gamma2, beta2, outf + off);
    }
}

// Round 7
// 549.773 us; speedup vs baseline: 1.2210x; 1.2210x over previous
//
#include <hip/hip_runtime.h>
#include <hip/hip_bf16.h>

// SwinBlock r7: XCD-chunked swizzle on GEMM grids, bf16 residual (no fp32 x1),
// mlp2ln2 retiled to 64x256 (3 blocks/CU), MLP in 2 chunks with hbuf in dead qkvb.
// B=32 H=W=56 C=256 NH=8 HD=32 WS=7 SS=3 L=49 nWin=64 -> 2048 windows, M=100352 rows.

typedef unsigned short ushort_t;
typedef short bf16x8 __attribute__((ext_vector_type(8)));
typedef float f32x4 __attribute__((ext_vector_type(4)));

__device__ __forceinline__ float bf2f(unsigned short u) {
    union { unsigned int i; float f; } x; x.i = ((unsigned int)u) << 16; return x.f;
}
__device__ __forceinline__ unsigned short f2bf(float f) {
    union { float f; unsigned int i; } x; x.f = f;
    unsigned int r = x.i + 0x7fffu + ((x.i >> 16) & 1u);   // RNE
    return (unsigned short)(r >> 16);
}
__device__ __forceinline__ bf16x8 pack8(float4 a, float4 b) {
    bf16x8 r;
    r[0] = (short)f2bf(a.x); r[1] = (short)f2bf(a.y);
    r[2] = (short)f2bf(a.z); r[3] = (short)f2bf(a.w);
    r[4] = (short)f2bf(b.x); r[5] = (short)f2bf(b.y);
    r[6] = (short)f2bf(b.z); r[7] = (short)f2bf(b.w);
    return r;
}
__device__ __forceinline__ void gl_lds16(const ushort_t* g, ushort_t* l) {
    __builtin_amdgcn_global_load_lds((const __attribute__((address_space(1))) void*)g,
                                     (__attribute__((address_space(3))) void*)l, 16, 0, 0);
}
// exact-erf GELU via Abramowitz-Stegun 7.1.26 (max |err| 1.5e-7)
__device__ __forceinline__ float gelu_f(float v) {
    float s = v * 0.70710678118654752f;
    float ax = fabsf(s);
    float t = __builtin_amdgcn_rcpf(1.0f + 0.3275911f * ax);
    float poly = ((((1.061405429f * t - 1.453152027f) * t + 1.421413741f) * t
                   - 0.284496736f) * t + 0.254829592f) * t;
    float y = 1.0f - poly * __expf(-ax * ax);
    float e = (s < 0.f) ? -y : y;
    return 0.5f * v * (1.0f + e);
}

// row m of the windowed/shifted activation -> element offset into x[B,H,W,C]
__device__ __forceinline__ long swin_src_off(int m) {
    int n = m / 49, l = m - n * 49;
    int b = n >> 6, win = n & 63;
    int wh = win >> 3, ww = win & 7;
    int i = l / 7, j = l - i * 7;
    int hs = wh * 7 + i + 3; if (hs >= 56) hs -= 56;   // roll(-3)
    int ws = ww * 7 + j + 3; if (ws >= 56) ws -= 56;
    return ((long)(b * 56 + hs) * 56 + ws) * 256;
}

// ---------------- prep: weights fp32 -> bf16 [N][K] (optional transpose) ----
template<int SRCT>
__global__ __launch_bounds__(256)
void convW(const float* __restrict__ src, ushort_t* __restrict__ dst, int N, int kshift)
{
    int idx = blockIdx.x * 256 + threadIdx.x;
    int kk = idx & ((1 << kshift) - 1), nn = idx >> kshift;
    float v = SRCT ? src[(long)kk * N + nn] : src[idx];
    dst[idx] = f2bf(v);
}

// ---------------- GEMM 128x128, BK=32, global_load_lds staging ----------------
// Linear grid + bijective XCD-chunked swizzle (requires gridDim.x % 8 == 0):
// each XCD owns a contiguous wg range; col-tile varies fastest within it, so an
// A row-stripe's NCOLS col-tiles all execute on the same XCD -> A L2-resident.
// AMODE 0: A bf16 [M][K] via gl_lds.  AMODE 1: A fp32 rows gathered via
// swin_src_off, reg-staged + packed to bf16 (K==256).
template<int ACT, int AMODE, int NCOLS>
__global__ __launch_bounds__(256)
void gemm128(const void* __restrict__ Av, const ushort_t* __restrict__ W,
             const float* __restrict__ bias, ushort_t* __restrict__ C,
             int M, int N, int K)
{
    __shared__ ushort_t As[128 * 32];
    __shared__ ushort_t Bs[128 * 32];
    const int t = threadIdx.x, lane = t & 63, wave = t >> 6;
    const int cpx = gridDim.x >> 3;
    const int wg = (blockIdx.x & 7) * cpx + (blockIdx.x >> 3);
    const int row0 = (wg / NCOLS) * 128, col0 = (wg % NCOLS) * 128;
    const int wm = (wave >> 1) * 64, wn = (wave & 1) * 64;

    const ushort_t* ag0; const ushort_t* ag1;
    const float* af0; const float* af1;
    if (AMODE == 0) {
        ag0 = (const ushort_t*)Av + (long)(row0 + (t >> 2)) * K + (t & 3) * 8;
        ag1 = (const ushort_t*)Av + (long)(row0 + 64 + (t >> 2)) * K + (t & 3) * 8;
    } else {
        af0 = (const float*)Av + swin_src_off(row0 + (t >> 2)) + (t & 3) * 8;
        af1 = (const float*)Av + swin_src_off(row0 + 64 + (t >> 2)) + (t & 3) * 8;
    }
    const ushort_t* bg0 = W + (long)(col0 + (t >> 2)) * K + (t & 3) * 8;
    const ushort_t* bg1 = W + (long)(col0 + 64 + (t >> 2)) * K + (t & 3) * 8;
    ushort_t* la0 = &As[t * 8];        ushort_t* la1 = &As[2048 + t * 8];
    ushort_t* lb0 = &Bs[t * 8];        ushort_t* lb1 = &Bs[2048 + t * 8];

    f32x4 acc[4][4] = {};
    for (int k0 = 0; k0 < K; k0 += 32) {
        bf16x8 a0, a1;
        if (AMODE == 1) {   // issue loads before the barrier: latency overlaps
            const float* p0 = af0 + k0;
            const float* p1 = af1 + k0;
            float4 x0 = *(const float4*)p0, x1 = *(const float4*)(p0 + 4);
            float4 x2 = *(const float4*)p1, x3 = *(const float4*)(p1 + 4);
            a0 = pack8(x0, x1); a1 = pack8(x2, x3);
        }
        __syncthreads();                 // previous tile fully consumed
        if (AMODE == 0) {
            gl_lds16(ag0 + k0, la0);
            gl_lds16(ag1 + k0, la1);
        } else {
            *(bf16x8*)la0 = a0;
            *(bf16x8*)la1 = a1;
        }
        gl_lds16(bg0 + k0, lb0);
        gl_lds16(bg1 + k0, lb1);
        __syncthreads();                 // staging resident
        bf16x8 af[4], bw[4];
        #pragma unroll
        for (int i = 0; i < 4; i++) {
            af[i] = *(const bf16x8*)&As[(wm + i * 16 + (lane & 15)) * 32 + (lane >> 4) * 8];
            bw[i] = *(const bf16x8*)&Bs[(wn + i * 16 + (lane & 15)) * 32 + (lane >> 4) * 8];
        }
        #pragma unroll
        for (int mi = 0; mi < 4; mi++)
            #pragma unroll
            for (int ni = 0; ni < 4; ni++)
                acc[mi][ni] = __builtin_amdgcn_mfma_f32_16x16x32_bf16(af[mi], bw[ni], acc[mi][ni], 0, 0, 0);
    }
    #pragma unroll
    for (int mi = 0; mi < 4; mi++)
        #pragma unroll
        for (int ni = 0; ni < 4; ni++) {
            const int c = col0 + wn + ni * 16 + (lane & 15);
            const float bv = bias[c];
            #pragma unroll
            for (int r = 0; r < 4; r++) {
                const int rr = row0 + wm + mi * 16 + (lane >> 4) * 4 + r;
                float v = acc[mi][ni][r] + bv;
                if (ACT) v = gelu_f(v);
                C[(long)rr * N + c] = f2bf(v);
            }
        }
}

// ---------------- MFMA attention: one wave per (window, head) ----------------
__global__ __launch_bounds__(64)
void attn_mfma(const ushort_t* __restrict__ qkv, const float* __restrict__ rpb,
               ushort_t* __restrict__ out)
{
    __shared__ ushort_t v_t[32 * 72];    // V^T [d][j], pad 72
    __shared__ ushort_t p_lds[64 * 72];  // P   [i][j], pad 72
    __shared__ float bias_s[169];

    const int blk = blockIdx.x;
    const int n = blk >> 3, h = blk & 7;
    const int l = threadIdx.x;           // 0..63
    const long wbase = (long)n * 49 * 768 + h * 32;
    const float scale = 0.17677669529663687f;   // 32^-0.5

    {
        int j = min(l, 48);
        const ushort_t* vr = qkv + wbase + (long)j * 768 + 512;
        #pragma unroll
        for (int c = 0; c < 4; c++) {
            bf16x8 vv = *(const bf16x8*)(vr + c * 8);
            #pragma unroll
            for (int e = 0; e < 8; e++) v_t[(c * 8 + e) * 72 + l] = (ushort_t)vv[e];
        }
    }
    for (int idx = l; idx < 169; idx += 64) bias_s[idx] = rpb[idx * 8 + h];
    __syncthreads();

    f32x4 s[4][4] = {};
    {
        bf16x8 aq[4], bk[4];
        #pragma unroll
        for (int mt = 0; mt < 4; mt++) {
            int i = min(mt * 16 + (l & 15), 48);
            aq[mt] = *(const bf16x8*)(qkv + wbase + (long)i * 768 + (l >> 4) * 8);
        }
        #pragma unroll
        for (int nt = 0; nt < 4; nt++) {
            int j = min(nt * 16 + (l & 15), 48);
            bk[nt] = *(const bf16x8*)(qkv + wbase + (long)j * 768 + 256 + (l >> 4) * 8);
        }
        #pragma unroll
        for (int mt = 0; mt < 4; mt++)
            #pragma unroll
            for (int nt = 0; nt < 4; nt++)
                s[mt][nt] = __builtin_amdgcn_mfma_f32_16x16x32_bf16(aq[mt], bk[nt], s[mt][nt], 0, 0, 0);
    }

    const int win = n & 63, wh = win >> 3, ww = win & 7;
    int yj[4], xj[4], regj[4]; bool jv[4];
    #pragma unroll
    for (int nt = 0; nt < 4; nt++) {
        int j = nt * 16 + (l & 15);
        jv[nt] = (j <= 48);
        int jc = min(j, 48);
        yj[nt] = jc / 7; xj[nt] = jc - yj[nt] * 7;
        int hs = wh * 7 + yj[nt], wsx = ww * 7 + xj[nt];
        regj[nt] = (hs < 49 ? 0 : (hs < 53 ? 1 : 2)) * 3 + (wsx < 49 ? 0 : (wsx < 53 ? 1 : 2));
    }
    float rinv[4][4];
    #pragma unroll
    for (int mt = 0; mt < 4; mt++) {
        #pragma unroll
        for (int r = 0; r < 4; r++) {
            int i = mt * 16 + (l >> 4) * 4 + r;
            int ic = min(i, 48);
            int yi = ic / 7, xi = ic - yi * 7;
            int hs = wh * 7 + yi, wsx = ww * 7 + xi;
            int regi = (hs < 49 ? 0 : (hs < 53 ? 1 : 2)) * 3 + (wsx < 49 ? 0 : (wsx < 53 ? 1 : 2));
            float val[4];
            #pragma unroll
            for (int nt = 0; nt < 4; nt++) {
                float v = s[mt][nt][r] * scale + bias_s[(yi - yj[nt] + 6) * 13 + (xi - xj[nt] + 6)];
                if (regi != regj[nt]) v -= 100.f;
                val[nt] = jv[nt] ? v : -1e30f;
            }
            float mx = fmaxf(fmaxf(val[0], val[1]), fmaxf(val[2], val[3]));
            #pragma unroll
            for (int off = 1; off <= 8; off <<= 1) mx = fmaxf(mx, __shfl_xor(mx, off));
            float sum = 0.f;
            #pragma unroll
            for (int nt = 0; nt < 4; nt++) { val[nt] = __expf(val[nt] - mx); sum += val[nt]; }
            #pragma unroll
            for (int off = 1; off <= 8; off <<= 1) sum += __shfl_xor(sum, off);
            rinv[mt][r] = 1.0f / sum;
            #pragma unroll
            for (int nt = 0; nt < 4; nt++)
                p_lds[i * 72 + nt * 16 + (l & 15)] = f2bf(val[nt]);
        }
    }
    __syncthreads();

    f32x4 o[4][2] = {};
    #pragma unroll
    for (int ks = 0; ks < 2; ks++) {
        bf16x8 pa[4], vb[2];
        #pragma unroll
        for (int mt = 0; mt < 4; mt++)
            pa[mt] = *(const bf16x8*)&p_lds[(mt * 16 + (l & 15)) * 72 + ks * 32 + (l >> 4) * 8];
        #pragma unroll
        for (int nt = 0; nt < 2; nt++)
            vb[nt] = *(const bf16x8*)&v_t[(nt * 16 + (l & 15)) * 72 + ks * 32 + (l >> 4) * 8];
        #pragma unroll
        for (int mt = 0; mt < 4; mt++)
            #pragma unroll
            for (int nt = 0; nt < 2; nt++)
                o[mt][nt] = __builtin_amdgcn_mfma_f32_16x16x32_bf16(pa[mt], vb[nt], o[mt][nt], 0, 0, 0);
    }
    #pragma unroll
    for (int mt = 0; mt < 4; mt++)
        #pragma unroll
        for (int r = 0; r < 4; r++) {
            int i = mt * 16 + (l >> 4) * 4 + r;
            if (i < 49) {
                float rs = rinv[mt][r];
                #pragma unroll
                for (int nt = 0; nt < 2; nt++) {
                    int d = nt * 16 + (l & 15);
                    out[((long)n * 49 + i) * 256 + h * 32 + d] = f2bf(o[mt][nt][r] * rs);
                }
            }
        }
}

// ------------- fused proj GEMM (128x256) + LN1 + residual -> x1 bf16 -------------
__global__ __launch_bounds__(512)
void projln1(const ushort_t* __restrict__ A, const ushort_t* __restrict__ W,
             const float* __restrict__ pb, const float* __restrict__ x,
             const float* __restrict__ gamma, const float* __restrict__ beta,
             ushort_t* __restrict__ x1b)
{
    __shared__ ushort_t As[128 * 32];
    __shared__ ushort_t Bs[256 * 32];
    __shared__ float red_s[128][4];
    __shared__ float red_ss[128][4];
    __shared__ int srow_s[128];
    const int t = threadIdx.x, lane = t & 63, w = t >> 6;
    const int row0 = blockIdx.x * 128;
    const int wm = (w >> 2) * 64, wn = (w & 3) * 64;

    if (t < 128) srow_s[t] = (int)(swin_src_off(row0 + t) >> 8);

    const ushort_t* ag = A + (long)(row0 + (t >> 2)) * 256 + (t & 3) * 8;
    f32x4 acc[4][4] = {};
    for (int k0 = 0; k0 < 256; k0 += 32) {
        __syncthreads();
        gl_lds16(ag + k0, &As[t * 8]);
        #pragma unroll
        for (int i = 0; i < 2; i++) {
            int u = i * 512 + t;
            gl_lds16(W + (long)(u >> 2) * 256 + k0 + (u & 3) * 8, &Bs[u * 8]);
        }
        __syncthreads();
        bf16x8 af[4], bw[4];
        #pragma unroll
        for (int i2 = 0; i2 < 4; i2++) {
            af[i2] = *(const bf16x8*)&As[(wm + i2 * 16 + (lane & 15)) * 32 + (lane >> 4) * 8];
            bw[i2] = *(const bf16x8*)&Bs[(wn + i2 * 16 + (lane & 15)) * 32 + (lane >> 4) * 8];
        }
        #pragma unroll
        for (int mi = 0; mi < 4; mi++)
            #pragma unroll
            for (int ni = 0; ni < 4; ni++)
                acc[mi][ni] = __builtin_amdgcn_mfma_f32_16x16x32_bf16(af[mi], bw[ni], acc[mi][ni], 0, 0, 0);
    }
    float pbv[4], g1v[4], be1v[4];
    #pragma unroll
    for (int ni = 0; ni < 4; ni++) {
        int col = wn + ni * 16 + (lane & 15);
        pbv[ni] = pb[col]; g1v[ni] = gamma[col]; be1v[ni] = beta[col];
    }
    #pragma unroll
    for (int mi = 0; mi < 4; mi++)
        #pragma unroll
        for (int rr = 0; rr < 4; rr++) {
            float s = 0.f, ss = 0.f;
            #pragma unroll
            for (int ni = 0; ni < 4; ni++) {
                float v = acc[mi][ni][rr] + pbv[ni];
                acc[mi][ni][rr] = v; s += v; ss += v * v;
            }
            #pragma unroll
            for (int off = 1; off <= 8; off <<= 1) { s += __shfl_xor(s, off); ss += __shfl_xor(ss, off); }
            if ((lane & 15) == 0) {
                int r = wm + mi * 16 + (lane >> 4) * 4 + rr;
                red_s[r][w & 3] = s; red_ss[r][w & 3] = ss;
            }
        }
    __syncthreads();
    #pragma unroll
    for (int mi = 0; mi < 4; mi++)
        #pragma unroll
        for (int rr = 0; rr < 4; rr++) {
            const int r = wm + mi * 16 + (lane >> 4) * 4 + rr;
            const float s = red_s[r][0] + red_s[r][1] + red_s[r][2] + red_s[r][3];
            const float ss = red_ss[r][0] + red_ss[r][1] + red_ss[r][2] + red_ss[r][3];
            const float mu = s * (1.0f / 256.0f);
            const float rstd = rsqrtf(ss * (1.0f / 256.0f) - mu * mu + 1e-5f);
            const long sp = srow_s[r];
            #pragma unroll
            for (int ni = 0; ni < 4; ni++) {
                int col = wn + ni * 16 + (lane & 15);
                float o = x[sp * 256 + col] + (acc[mi][ni][rr] - mu) * rstd * g1v[ni] + be1v[ni];
                x1b[sp * 256 + col] = f2bf(o);
            }
        }
}

// ------- fused mlp2 GEMM (64x256, K=1024) + LN2 + residual(bf16 x1), fp32 out -----
// 256 threads / 4 waves; wave w owns all 64 rows x cols [w*64, w*64+64).
__global__ __launch_bounds__(256)
void mlp2ln2(const ushort_t* __restrict__ A, const ushort_t* __restrict__ W,
             const float* __restrict__ pb, const ushort_t* __restrict__ x1res,
             const float* __restrict__ gamma, const float* __restrict__ beta,
             float* __restrict__ out)
{
    __shared__ ushort_t As[64 * 32];
    __shared__ ushort_t Bs[256 * 32];
    __shared__ float red_s[64][4];
    __shared__ float red_ss[64][4];
    const int t = threadIdx.x, lane = t & 63, w = t >> 6;
    const int row0 = blockIdx.x * 64;
    const int wn = w * 64;

    const ushort_t* ag = A + (long)(row0 + (t >> 2)) * 1024 + (t & 3) * 8;
    f32x4 acc[4][4] = {};
    for (int k0 = 0; k0 < 1024; k0 += 32) {
        __syncthreads();
        gl_lds16(ag + k0, &As[t * 8]);
        #pragma unroll
        for (int i = 0; i < 4; i++) {
            int u = i * 256 + t;
            gl_lds16(W + (long)(u >> 2) * 1024 + k0 + (u & 3) * 8, &Bs[u * 8]);
        }
        __syncthreads();
        bf16x8 af[4], bw[4];
        #pragma unroll
        for (int i2 = 0; i2 < 4; i2++) {
            af[i2] = *(const bf16x8*)&As[(i2 * 16 + (lane & 15)) * 32 + (lane >> 4) * 8];
            bw[i2] = *(const bf16x8*)&Bs[(wn + i2 * 16 + (lane & 15)) * 32 + (lane >> 4) * 8];
        }
        #pragma unroll
        for (int mi = 0; mi < 4; mi++)
            #pragma unroll
            for (int ni = 0; ni < 4; ni++)
                acc[mi][ni] = __builtin_amdgcn_mfma_f32_16x16x32_bf16(af[mi], bw[ni], acc[mi][ni], 0, 0, 0);
    }
    float pbv[4], g2v[4], be2v[4];
    #pragma unroll
    for (int ni = 0; ni < 4; ni++) {
        int col = wn + ni * 16 + (lane & 15);
        pbv[ni] = pb[col]; g2v[ni] = gamma[col]; be2v[ni] = beta[col];
    }
    #pragma unroll
    for (int mi = 0; mi < 4; mi++)
        #pragma unroll
        for (int rr = 0; rr < 4; rr++) {
            float s = 0.f, ss = 0.f;
            #pragma unroll
            for (int ni = 0; ni < 4; ni++) {
                float v = acc[mi][ni][rr] + pbv[ni];
                acc[mi][ni][rr] = v; s += v; ss += v * v;
            }
            #pragma unroll
            for (int off = 1; off <= 8; off <<= 1) { s += __shfl_xor(s, off); ss += __shfl_xor(ss, off); }
            if ((lane & 15) == 0) {
                int r = mi * 16 + (lane >> 4) * 4 + rr;
                red_s[r][w] = s; red_ss[r][w] = ss;
            }
        }
    __syncthreads();
    #pragma unroll
    for (int mi = 0; mi < 4; mi++)
        #pragma unroll
        for (int rr = 0; rr < 4; rr++) {
            const int r = mi * 16 + (lane >> 4) * 4 + rr;
            const float s = red_s[r][0] + red_s[r][1] + red_s[r][2] + red_s[r][3];
            const float ss = red_ss[r][0] + red_ss[r][1] + red_ss[r][2] + red_ss[r][3];
            const float mu = s * (1.0f / 256.0f);
            const float rstd = rsqrtf(ss * (1.0f / 256.0f) - mu * mu + 1e-5f);
            const long gr = row0 + r;
            #pragma unroll
            for (int ni = 0; ni < 4; ni++) {
                int col = wn + ni * 16 + (lane & 15);
                out[gr * 256 + col] = bf2f(x1res[gr * 256 + col])
                                    + (acc[mi][ni][rr] - mu) * rstd * g2v[ni] + be2v[ni];
            }
        }
}

extern "C" void kernel_launch(void* const* d_in, const int* in_sizes, int n_in,
                              void* d_out, int out_size, void* d_ws, size_t ws_size,
                              hipStream_t stream) {
    const float* x      = (const float*)d_in[0];
    const float* qkv_w  = (const float*)d_in[1];
    const float* qkv_b  = (const float*)d_in[2];
    const float* proj_w = (const float*)d_in[3];
    const float* proj_b = (const float*)d_in[4];
    const float* rpb    = (const float*)d_in[5];
    const float* gamma1 = (const float*)d_in[6];
    const float* beta1  = (const float*)d_in[7];
    const float* w1     = (const float*)d_in[8];
    const float* b1     = (const float*)d_in[9];
    const float* w2     = (const float*)d_in[10];
    const float* b2     = (const float*)d_in[11];
    const float* gamma2 = (const float*)d_in[12];
    const float* beta2  = (const float*)d_in[13];
    float* outf = (float*)d_out;

    // d_out[0,51.4M) holds attnout (bf16) until projln1 consumes it; final fp32
    // out writes happen after (chunk 0 overlaps the dead attnout region).
    ushort_t* attnout = (ushort_t*)d_out;

    char* ws = (char*)d_ws;
    ushort_t* qkvb  = (ushort_t*)ws;                      // [0,154.1M)  qkv -> attn (dead after)
    ushort_t* hbuf  = (ushort_t*)ws;                      // [0,102.8M)  per-MLP-chunk hidden (reuses qkvb)
    ushort_t* x1b   = (ushort_t*)(ws + 154140672ULL);     // [154.1,205.5M) projln1 -> MLP + residual
    ushort_t* wqkvb = (ushort_t*)(ws + 205520896ULL);     // bf16 weights [N][K]
    ushort_t* wprojb= (ushort_t*)(ws + 205914112ULL);
    ushort_t* w1t   = (ushort_t*)(ws + 206045184ULL);
    ushort_t* w2t   = (ushort_t*)(ws + 206569472ULL);

    const int M = 100352, MC = 50176;   // 2 MLP chunks
    dim3 blk(256);
    // prep: bf16 weights
    convW<0><<<dim3(768),  blk, 0, stream>>>(qkv_w,  wqkvb,  768,  8);   // [768][256]
    convW<0><<<dim3(256),  blk, 0, stream>>>(proj_w, wprojb, 256,  8);   // [256][256]
    convW<1><<<dim3(1024), blk, 0, stream>>>(w1,     w1t,    1024, 8);   // -> [1024][256]
    convW<1><<<dim3(1024), blk, 0, stream>>>(w2,     w2t,    256, 10);   // -> [256][1024]
    // 1. qkv = gather(x) @ Wqkv^T + b  (XCD-chunked swizzle, NCOLS=6, 4704 blocks)
    gemm128<0, 1, 6><<<dim3(4704), blk, 0, stream>>>(x, wqkvb, qkv_b, qkvb, M, 768, 256);
    // 2. windowed attention
    attn_mfma<<<dim3(16384), dim3(64), 0, stream>>>(qkvb, rpb, attnout);
    // 3. proj + LN1 + residual -> x1 bf16 (scattered to natural row order)
    projln1<<<dim3(784), dim3(512), 0, stream>>>(attnout, wprojb, proj_b, x,
                                                 gamma1, beta1, x1b);
    // 4/5. MLP in 2 M-chunks; h chunk (102.8MB) lives in dead qkvb, ~L3-resident
    for (int c2 = 0; c2 < 2; c2++) {
        const long off = (long)c2 * MC * 256;
        gemm128<1, 0, 8><<<dim3(3136), blk, 0, stream>>>(x1b + off, w1t, b1, hbuf, MC, 1024, 256);
        mlp2ln2<<<dim3(784), blk, 0, stream>>>(hbuf, w2t, b2, x1b + off,
                                               gamma2, beta2, outf + off);
    }
}